// Round 19
// baseline (183.780 us; speedup 1.0000x reference)
//
#include <hip/hip_runtime.h>
#include <math.h>

#define NH 12
#define SEQ 2048
#define DM 768
#define HD 64
#define NB 2
#define MT (NB * SEQ)          // 4096 rows
// Q pre-scale: 1/sqrt(64) * log2(e)  -> softmax via exp2
#define QSCL 0.18033688011112042591999058512524f

typedef short bf16x8 __attribute__((ext_vector_type(8)));
typedef float f32x16 __attribute__((ext_vector_type(16)));
typedef unsigned u32x2 __attribute__((ext_vector_type(2)));

__device__ __forceinline__ unsigned short bf16_rne(float x) {
    unsigned u = __float_as_uint(x);
    u += 0x7fffu + ((u >> 16) & 1u);
    return (unsigned short)(u >> 16);
}
__device__ __forceinline__ float bf16_tof(short h) {
    return __uint_as_float(((unsigned)(unsigned short)h) << 16);
}
// pack two f32 -> one u32 of 2x bf16 (RNE); no builtin on gfx950 (m240)
__device__ __forceinline__ unsigned cvtpk(float lo, float hi) {
    unsigned r;
    asm("v_cvt_pk_bf16_f32 %0, %1, %2" : "=v"(r) : "v"(lo), "v"(hi));
    return r;
}

__device__ __forceinline__ void gl_lds16(const void* g, void* s) {
    __builtin_amdgcn_global_load_lds(
        (const __attribute__((address_space(1))) unsigned int*)g,
        (__attribute__((address_space(3))) unsigned int*)s, 16, 0, 0);
}

__device__ __forceinline__ f32x16 mfma32(bf16x8 a, bf16x8 b, f32x16 c) {
    return __builtin_amdgcn_mfma_f32_32x32x16_bf16(a, b, c, 0, 0, 0);
}

// GEMM frag read: 128-B LDS rows (BK=64), 8 blocks of 16 B
__device__ __forceinline__ bf16x8 gfrag128(const char* base, int row, int physblk) {
    return *(const bf16x8*)(base + row * 128 + physblk * 16);
}
// Attention frag read: 128-B LDS rows, 8 blocks of 16 B, key row&7
__device__ __forceinline__ bf16x8 afrag(const short* base, int row, int blk) {
    return *(const bf16x8*)(base + row * 64 + ((blk ^ (row & 7)) << 3));
}

// ---------------------------------------------------------------------------
// Merged pre-pass. Blocks [0,1536): x fp32 -> bf16 (key (m>>1)&3).
// Blocks [1536, 2688): W transpose+convert, z = (b-1536)/288.
// z<3 (Wq,Wk,Wv) -> wqkv region; z==3 (Wo) -> wo region.
// ---------------------------------------------------------------------------
__global__ __launch_bounds__(256)
void conv_all(const float* __restrict__ x,
              const float* __restrict__ Wq, const float* __restrict__ Wk,
              const float* __restrict__ Wv, const float* __restrict__ Wo,
              short* __restrict__ xg, short* __restrict__ wqkv,
              short* __restrict__ wo)
{
    int b = blockIdx.x;
    if (b < 1536) {
        const int idx = b * 256 + threadIdx.x;   // 4096*96
        const int m = idx / 96, bk = idx % 96;
        const float* src = x + (size_t)m * DM + bk * 8;
        float4 v0 = *(const float4*)src;
        float4 v1 = *(const float4*)(src + 4);
        const float vv[8] = {v0.x, v0.y, v0.z, v0.w, v1.x, v1.y, v1.z, v1.w};
        union { short s[8]; int4 q; } hh;
#pragma unroll
        for (int j = 0; j < 8; j++) hh.s[j] = (short)bf16_rne(vv[j]);
        const int pb = (bk & ~3) | ((bk & 3) ^ ((m >> 1) & 3));
        *(int4*)(xg + (size_t)m * DM + pb * 8) = hh.q;
    } else {
        b -= 1536;
        const int z = b / 288;
        const float* __restrict__ W = (z == 0) ? Wq : (z == 1) ? Wk : (z == 2) ? Wv : Wo;
        short* __restrict__ wdst = (z == 3) ? wo : (wqkv + (size_t)z * 589824);
        const int idx = (b % 288) * 256 + threadIdx.x;   // 96*768
        const int n = idx % 768, bk = idx / 768;
        union { short s[8]; int4 q; } hh;
#pragma unroll
        for (int j = 0; j < 8; j++) hh.s[j] = (short)bf16_rne(W[(size_t)(bk * 8 + j) * DM + n]);
        const int pb = (bk & ~3) | ((bk & 3) ^ ((n >> 1) & 3));
        *(int4*)(wdst + (size_t)n * DM + pb * 8) = hh.q;
    }
}

// ---------------------------------------------------------------------------
// QKV K-loop — R28 config (proven: BK=64, 12 iters, 8 MFMA/wave per
// barrier; -1.3us vs BK=32). Tile 64M x 128N, 6 gl_lds/iter, one
// barrier/iter. LDS 48 KB -> 3 blocks/CU. Swizzle: sel=(row>>1)&3 valid
// since all row offsets (32/64/96) are 0 mod 8. SWAP=true computes Y^T.
// ---------------------------------------------------------------------------
template<bool SWAP>
__device__ __forceinline__ void qkv_loop(const char* pA, const char* pB,
                                         char* As, char* Bs,
                                         int t, f32x16* acc)
{
    const int w = t >> 6, l = t & 63;
    const int q32 = l & 31, half = l >> 5;
    const int sel = (q32 >> 1) & 3;
    const int arow  = 32 * (w & 1) + q32;
    const int brow0 = 64 * (w >> 1) + q32;
    char* const dA = As + w * 1024;   // wave-uniform DMA dest (HW adds lane*16)
    char* const dB = Bs + w * 1024;

    auto stage = [&](int ki, int buf) {
        const size_t cb = (size_t)ki * 128;
        gl_lds16(pA + cb,             dA + buf * 8192);
        gl_lds16(pA + 32 * 1536 + cb, dA + buf * 8192 + 4096);
        gl_lds16(pB + cb,             dB + buf * 16384);
        gl_lds16(pB + 32 * 1536 + cb, dB + buf * 16384 + 4096);
        gl_lds16(pB + 64 * 1536 + cb, dB + buf * 16384 + 8192);
        gl_lds16(pB + 96 * 1536 + cb, dB + buf * 16384 + 12288);
    };

    stage(0, 0);
    __syncthreads();

    for (int ki = 0; ki < 12; ki++) {
        const int cur = ki & 1;
        if (ki < 11) stage(ki + 1, cur ^ 1);
        const char* sA = As + cur * 8192;
        const char* sB = Bs + cur * 16384;
#pragma unroll
        for (int ks2 = 0; ks2 < 4; ks2++) {
            const int b = ks2 * 2 + half;
            const int blk = (b & ~3) | ((b & 3) ^ sel);
            bf16x8 a  = gfrag128(sA, arow, blk);
            bf16x8 b0 = gfrag128(sB, brow0, blk);
            bf16x8 b1 = gfrag128(sB, brow0 + 32, blk);
            if (SWAP) {
                acc[0] = mfma32(b0, a, acc[0]);
                acc[1] = mfma32(b1, a, acc[1]);
            } else {
                acc[0] = mfma32(a, b0, acc[0]);
                acc[1] = mfma32(a, b1, acc[1]);
            }
        }
        __syncthreads();
    }
}

// ---------------------------------------------------------------------------
// QKV GEMM. grid (6, 64, 3), block 256 (4 waves, each 32M x 64N).
// R29: __launch_bounds__(256, 3) — LDS (48 KB) already caps at 3
// blocks/CU; declaring it frees the allocator (R24 mechanism: -2.3us
// on attn). z<2 computes Y^T -> Q/K epilogue [b][h][s][64] (key s&7).
// z==2 computes Y -> V^T epilogue [b][h][hd][2048] (key hd&7).
// ---------------------------------------------------------------------------
__global__ __launch_bounds__(256, 3)
void gemm_qkv(const short* __restrict__ xg, const short* __restrict__ wqkv,
              const float* __restrict__ bq, const float* __restrict__ bkv,
              const float* __restrict__ bv,
              short* __restrict__ qg, short* __restrict__ kg, short* __restrict__ vg)
{
    const int z = blockIdx.z;
    const short* __restrict__ Bw = wqkv + (size_t)z * 589824;
    const float* __restrict__ bias = (z == 0) ? bq : (z == 1) ? bkv : bv;

    __shared__ char As[16384], Bs[32768];
    const int t = threadIdx.x, w = t >> 6, l = t & 63;
    const int m0 = blockIdx.y * 64, n0 = blockIdx.x * 128;
    const int q32 = l & 31, half = l >> 5;

    // BK=64 staging: thread t covers row t>>3, 16-B chunk t&7 of a 128-B row
    const char* pA = (const char*)xg + (size_t)(m0 + (t >> 3)) * 1536 + (t & 7) * 16;
    const char* pB = (const char*)Bw + (size_t)(n0 + (t >> 3)) * 1536 + (t & 7) * 16;

    f32x16 acc[2];
#pragma unroll
    for (int i = 0; i < 2; i++)
#pragma unroll
        for (int r = 0; r < 16; r++) acc[i][r] = 0.f;

    if (z == 2) {
        qkv_loop<false>(pA, pB, As, Bs, t, acc);
        // V^T epilogue: reg-rows = m (4 consecutive s) -> uint2 stores
        const int nbase = n0 + 64 * (w >> 1);
        const int h = nbase >> 6;
        const int mbase = m0 + 32 * (w & 1) + 4 * half;
        const int bb = mbase >> 11;
#pragma unroll
        for (int nt = 0; nt < 2; nt++) {
            const int hd = 32 * nt + q32;
            const float bia = bias[nbase + hd];
            short* vrow = vg + ((size_t)(bb * NH + h) * HD + hd) * SEQ;
#pragma unroll
            for (int g = 0; g < 4; g++) {
                const int ss0 = (mbase & 2047) + 8 * g;
                union { unsigned short u[4]; uint2 q; } pk;
#pragma unroll
                for (int j = 0; j < 4; j++)
                    pk.u[j] = bf16_rne(acc[nt][4 * g + j] + bia);
                const int blk = ss0 >> 3;
                const int phys = (blk & ~7) | ((blk & 7) ^ (hd & 7));
                *(uint2*)(vrow + phys * 8 + (ss0 & 7)) = pk.q;
            }
        }
    } else {
        qkv_loop<true>(pA, pB, As, Bs, t, acc);
        // Q/K epilogue: reg-rows = n (4 consecutive hd) -> uint2 stores
        short* dst = (z == 0) ? qg : kg;
        const float scl = (z == 0) ? QSCL : 1.0f;
        const int mcol = m0 + 32 * (w & 1) + q32;
        const int bb = mcol >> 11, ss = mcol & 2047;
        const int h = (n0 + 64 * (w >> 1)) >> 6;
        short* drow = dst + ((size_t)(bb * NH + h) * SEQ + ss) * HD;
#pragma unroll
        for (int nt = 0; nt < 2; nt++)
#pragma unroll
            for (int g = 0; g < 4; g++) {
                const int hd0 = 32 * nt + 8 * g + 4 * half;
                float4 b4 = *(const float4*)&bias[(h << 6) + hd0];
                const float bb4[4] = {b4.x, b4.y, b4.z, b4.w};
                union { unsigned short u[4]; uint2 q; } pk;
#pragma unroll
                for (int j = 0; j < 4; j++)
                    pk.u[j] = bf16_rne((acc[nt][4 * g + j] + bb4[j]) * scl);
                const int phys = (hd0 >> 3) ^ (ss & 7);
                *(uint2*)(drow + phys * 8 + (hd0 & 7)) = pk.q;
            }
    }
}

// ---------------------------------------------------------------------------
// MFMA flash attention — exact R24 kernel (proven 47-50 us, best).
// R21 pipeline + __launch_bounds__(256, 3). exp2f is OCML — precision
// load-bearing (R22 lesson). Pipeline: prefetch(k+2) -> exp/pack(k) ->
// QK(k+1) -> PV(k); 3-slot ring, rotating pointers, z16-C-operand,
// T1 XCD remap. grid 768.
// ---------------------------------------------------------------------------
__global__ __launch_bounds__(256, 3)
void attn_mfma(const short* __restrict__ qg, const short* __restrict__ kg,
               const short* __restrict__ vg,
               short* __restrict__ opart, float* __restrict__ lpart)
{
    __shared__ __align__(16) short lds[24576];   // 48 KB: 3 slots of 16 KB (K 8KB + V 8KB)
    short* const sl0 = lds + 8192;
    short* const sl1 = lds + 16384;
    short* const sl2 = lds;                      // Q region until tile 2

    const int t = threadIdx.x, w = t >> 6, l = t & 63;
    const int f = (blockIdx.x & 7) * 96 + (blockIdx.x >> 3);   // T1 bijective remap
    const int q0 = (f & 15) * 128;
    const int bh = (f >> 4) % 24;
    const int ks = f / 384;
    const char* qp = (const char*)(qg + (size_t)bh * SEQ * HD);
    const char* kp = (const char*)(kg + (size_t)bh * SEQ * HD);
    const char* vp = (const char*)(vg + (size_t)bh * HD * SEQ);
    const int kbase = ks * 1024;

    auto stage_kv = [&](int tile, short* dst) {
        const int kb0 = kbase + tile * 64;
#pragma unroll
        for (int i = 0; i < 2; i++) {
            gl_lds16(kp + (size_t)(kb0 + w * 16 + i * 8) * 128 + l * 16,
                     (char*)dst + (w * 16 + i * 8) * 128);
            gl_lds16(vp + (size_t)(w * 16 + i * 8 + (l >> 3)) * 4096 + kb0 * 2 + (l & 7) * 16,
                     (char*)(dst + 4096) + (w * 16 + i * 8) * 128);
        }
    };

    // prologue: Q (wave-local rows) + tiles 0,1
#pragma unroll
    for (int i = 0; i < 4; i++)
        gl_lds16(qp + (size_t)(q0 + w * 32 + i * 8) * 128 + l * 16,
                 (char*)lds + (w * 32 + i * 8) * 128);
    stage_kv(0, sl0);
    stage_kv(1, sl1);

    asm volatile("s_waitcnt vmcnt(8)" ::: "memory");   // own Q DMA done (8 K/V ops in flight)

    const int half = l >> 5;
    const int q = l & 31;
    bf16x8 qf[4];
#pragma unroll
    for (int s = 0; s < 4; s++)
        qf[s] = afrag(lds, w * 32 + q, half + s * 2);
    __syncthreads();   // drains tiles 0,1 DMA; all waves' Q reads done (slot2 reusable)

    f32x16 oacc[2], lacc, z16;
#pragma unroll
    for (int r = 0; r < 16; r++) z16[r] = 0.f;
#pragma unroll
    for (int nt = 0; nt < 2; nt++)
#pragma unroll
        for (int r = 0; r < 16; r++) oacc[nt][r] = 0.f;
#pragma unroll
    for (int r = 0; r < 16; r++) lacc[r] = 0.f;

    bf16x8 onesf;
#pragma unroll
    for (int j = 0; j < 8; j++) onesf[j] = (short)0x3F80;   // bf16 1.0

    // rotating slot pointers: at iter k, scur=slot(k), snxt=slot(k+1),
    // spre=slot(k+2)==slot(k-1)
    short* scur = sl0;
    short* snxt = sl1;
    short* spre = sl2;

    // QK(0): first MFMA of each chain takes z16 as C (no zero-init movs)
    f32x16 sacc[2];
#pragma unroll
    for (int nt = 0; nt < 2; nt++)
        sacc[nt] = mfma32(afrag(sl0, nt * 32 + q, half), qf[0], z16);
#pragma unroll
    for (int s = 1; s < 4; s++)
#pragma unroll
        for (int nt = 0; nt < 2; nt++)
            sacc[nt] = mfma32(afrag(sl0, nt * 32 + q, half + s * 2), qf[s], sacc[nt]);

    for (int kti = 0; kti < 16; kti++) {
        // prefetch tile kti+2 into spre (== slot of tile kti-1) — issued
        // FIRST so the DMA has the exp/pack + MFMA phases to land
        if (kti < 14) stage_kv(kti + 2, spre);

        // P(kti) = exp2(S) in place (OCML exp2f — precision load-bearing)
#pragma unroll
        for (int nt = 0; nt < 2; nt++)
#pragma unroll
            for (int r = 0; r < 16; r++) sacc[nt][r] = exp2f(sacc[nt][r]);

        // pack all 4 PV A-fragments (T12); sacc is dead afterwards
        bf16x8 pfs[4];
#pragma unroll
        for (int s = 0; s < 4; s++) {
            const int nt = s >> 1;
            const int rb = (s & 1) * 8;
            const unsigned p0 = cvtpk(sacc[nt][rb + 0], sacc[nt][rb + 1]);
            const unsigned p1 = cvtpk(sacc[nt][rb + 2], sacc[nt][rb + 3]);
            const unsigned p2 = cvtpk(sacc[nt][rb + 4], sacc[nt][rb + 5]);
            const unsigned p3 = cvtpk(sacc[nt][rb + 6], sacc[nt][rb + 7]);
            const u32x2 w02 = __builtin_amdgcn_permlane32_swap(p0, p2, false, false);
            const u32x2 w13 = __builtin_amdgcn_permlane32_swap(p1, p3, false, false);
            union { unsigned u[4]; bf16x8 v; } pf;
            pf.u[0] = w02[0];   // keys 16s+8*half+{0,1}
            pf.u[1] = w13[0];   // keys 16s+8*half+{2,3}
            pf.u[2] = w02[1];   // keys 16s+8*half+{4,5}
            pf.u[3] = w13[1];   // keys 16s+8*half+{6,7}
            pfs[s] = pf.v;
        }

        // QK(kti+1) into reused sacc — fuses with PV below into one MFMA streak
        if (kti < 15) {
#pragma unroll
            for (int nt = 0; nt < 2; nt++)
                sacc[nt] = mfma32(afrag(snxt, nt * 32 + q, half), qf[0], z16);
#pragma unroll
            for (int s = 1; s < 4; s++)
#pragma unroll
                for (int nt = 0; nt < 2; nt++)
                    sacc[nt] = mfma32(afrag(snxt, nt * 32 + q, half + s * 2), qf[s], sacc[nt]);
        }

        // PV(kti): O += P V ; l += P @ ones
        const short* vc = scur + 4096;
#pragma unroll
        for (int s = 0; s < 4; s++) {
            lacc = mfma32(pfs[s], onesf, lacc);
#pragma unroll
            for (int nt2 = 0; nt2 < 2; nt2++)
                oacc[nt2] = mfma32(pfs[s], afrag(vc, nt2 * 32 + q, half + s * 2), oacc[nt2]);
        }
        __syncthreads();   // drains prefetch DMA; all waves done with scur

        short* tmp = scur; scur = snxt; snxt = spre; spre = tmp;
    }

    // epilogue: unnormalized partials
    const size_t base = (size_t)(ks * 24 + bh) * SEQ;
#pragma unroll
    for (int r = 0; r < 16; r++) {
        const int row = q0 + w * 32 + (r & 3) + 8 * (r >> 2) + 4 * half;
#pragma unroll
        for (int nt = 0; nt < 2; nt++)
            opart[(base + row) * 64 + nt * 32 + q] = (short)bf16_rne(oacc[nt][r]);
        if (q == 0) lpart[base + row] = lacc[r];
    }
}

// ---------------------------------------------------------------------------
// Combine K-split partials: ag = (O0+O1)/(l0+l1), bf16, key (m>>1)&3.
// grid 1536, block 256 (thread = 8 hd of one row).
// ---------------------------------------------------------------------------
__global__ __launch_bounds__(256)
void attn_reduce(const short* __restrict__ opart, const float* __restrict__ lpart,
                 short* __restrict__ ag)
{
    const int idx = blockIdx.x * 256 + threadIdx.x;   // 49152*8
    const int cg = idx & 7, row = idx >> 3;
    const int bh = row >> 11, s = row & 2047;
    union { short s[8]; int4 q; } a, b, o;
    a.q = *(const int4*)(opart + ((size_t)bh * SEQ + s) * 64 + cg * 8);
    b.q = *(const int4*)(opart + ((size_t)(24 + bh) * SEQ + s) * 64 + cg * 8);
    const float inv = 1.0f / (lpart[(size_t)bh * SEQ + s] + lpart[(size_t)(24 + bh) * SEQ + s]);
#pragma unroll
    for (int j = 0; j < 8; j++)
        o.s[j] = (short)bf16_rne((bf16_tof(a.s[j]) + bf16_tof(b.s[j])) * inv);
    const int bb = bh / NH, h = bh % NH;
    const int m = bb * SEQ + s;
    const int blk = h * 8 + cg;
    const int phys = (blk & ~3) | ((blk & 3) ^ ((m >> 1) & 3));
    *(int4*)(ag + (size_t)m * DM + phys * 8) = o.q;
}

// ---------------------------------------------------------------------------
// Output projection — R26 config + R29 __launch_bounds__(256, 5) (LDS
// 32 KB caps at 5 blocks/CU; declare it). BK=64, 12 iters, 4 MFMA/wave
// per barrier. Tile 64M x 64N, grid (12, 64). Computed transposed
// (reg-rows = n) -> float4 epilogue.
// ---------------------------------------------------------------------------
__global__ __launch_bounds__(256, 5)
void gemm_out(const short* __restrict__ ag, const short* __restrict__ wt3,
              const float* __restrict__ bias, float* __restrict__ out)
{
    __shared__ char As[16384], Bs[16384];
    const int t = threadIdx.x, w = t >> 6, l = t & 63;
    const int m0 = blockIdx.y * 64, n0 = blockIdx.x * 64;
    const int q32 = l & 31, half = l >> 5;
    const int sel = (q32 >> 1) & 3;

    // BK=64 staging: thread t covers row t>>3, 16-B chunk t&7 of a 128-B row
    const char* pA = (const char*)ag  + (size_t)(m0 + (t >> 3)) * 1536 + (t & 7) * 16;
    const char* pB = (const char*)wt3 + (size_t)(n0 + (t >> 3)) * 1536 + (t & 7) * 16;
    char* const dA = As + w * 1024;   // wave-uniform DMA dest
    char* const dB = Bs + w * 1024;

    const int arow = 32 * (w & 1) + q32;
    const int brow = 32 * (w >> 1) + q32;

    f32x16 acc;
#pragma unroll
    for (int r = 0; r < 16; r++) acc[r] = 0.f;

    auto stage = [&](int ki, int buf) {
        const size_t cb = (size_t)ki * 128;
        gl_lds16(pA + cb,             dA + buf * 8192);          // rows 0-31
        gl_lds16(pA + 32 * 1536 + cb, dA + buf * 8192 + 4096);   // rows 32-63
        gl_lds16(pB + cb,             dB + buf * 8192);
        gl_lds16(pB + 32 * 1536 + cb, dB + buf * 8192 + 4096);
    };

    stage(0, 0);
    __syncthreads();

    for (int ki = 0; ki < 12; ki++) {
        const int cur = ki & 1;
        if (ki < 11) stage(ki + 1, cur ^ 1);
        const char* sA = As + cur * 8192;
        const char* sB = Bs + cur * 8192;
#pragma unroll
        for (int ks2 = 0; ks2 < 4; ks2++) {
            const int b = ks2 * 2 + half;
            const int blk = (b & ~3) | ((b & 3) ^ sel);
            acc = mfma32(gfrag128(sB, brow, blk), gfrag128(sA, arow, blk), acc);
        }
        __syncthreads();
    }

    const int mcol = m0 + 32 * (w & 1) + q32;
    const int nb0 = n0 + 32 * (w >> 1) + 4 * half;
#pragma unroll
    for (int g = 0; g < 4; g++) {
        const int ng = nb0 + 8 * g;
        float4 b4 = *(const float4*)&bias[ng];
        float4 o;
        o.x = acc[4 * g + 0] + b4.x;
        o.y = acc[4 * g + 1] + b4.y;
        o.z = acc[4 * g + 2] + b4.z;
        o.w = acc[4 * g + 3] + b4.w;
        *(float4*)&out[(size_t)mcol * DM + ng] = o;
    }
}

// ---------------------------------------------------------------------------
// Workspace layout (lifetime-aliased; R15 placement). Units: shorts.
//   wo    @ 0          size 589824      (conv -> gemm_out)
//   qg    @ 589824     size BUF         (qkv -> attn)
//   kg, vg             size BUF each
//   opart @ vg+BUF     size 2*24*2048*64 = 6291456    (attn -> reduce)
//   lpart @ opart+6291456   size 98304 floats         (attn -> reduce)
//   xg    @ = opart    size BUF         (conv -> qkv; dead before attn)  [alias]
//   wqkv  @ xg+BUF     size 3*589824    (conv -> qkv; dead before attn)  [alias]
//   ag    @ = qg       size BUF         (reduce -> out; qg dead)         [alias]
// ---------------------------------------------------------------------------
extern "C" void kernel_launch(void* const* d_in, const int* in_sizes, int n_in,
                              void* d_out, int out_size, void* d_ws, size_t ws_size,
                              hipStream_t stream)
{
    const float* x  = (const float*)d_in[0];
    const float* Wq = (const float*)d_in[1];
    const float* bq = (const float*)d_in[2];
    const float* Wk = (const float*)d_in[3];
    const float* bk = (const float*)d_in[4];
    const float* Wv = (const float*)d_in[5];
    const float* bv = (const float*)d_in[6];
    const float* Wo = (const float*)d_in[7];
    const float* bo = (const float*)d_in[8];
    float* out = (float*)d_out;

    const size_t BUF = (size_t)MT * DM;   // 3,145,728 elements
    short* base  = (short*)d_ws;
    short* wo    = base;
    short* qg    = base + 589824;
    short* kg    = qg + BUF;
    short* vg    = kg + BUF;
    short* opart = vg + BUF;                         // 2x partials
    float* lpart = (float*)(opart + (size_t)2 * 24 * SEQ * HD);
    short* xg    = opart;                            // alias (dead before attn)
    short* wqkv  = xg + BUF;                         // alias (dead before attn)
    short* ag    = qg;                               // alias (qg dead at reduce)

    conv_all<<<2688, 256, 0, stream>>>(x, Wq, Wk, Wv, Wo, xg, wqkv, wo);
    gemm_qkv<<<dim3(6, 64, 3), 256, 0, stream>>>(xg, wqkv, bq, bk, bv, qg, kg, vg);
    attn_mfma<<<768, 256, 0, stream>>>(qg, kg, vg, opart, lpart);
    attn_reduce<<<1536, 256, 0, stream>>>(opart, lpart, ag);
    gemm_out<<<dim3(12, 64), 256, 0, stream>>>(ag, wo, bo, out);
}

// Round 20
// 179.355 us; speedup vs baseline: 1.0247x; 1.0247x over previous
//
#include <hip/hip_runtime.h>
#include <math.h>

#define NH 12
#define SEQ 2048
#define DM 768
#define HD 64
#define NB 2
#define MT (NB * SEQ)          // 4096 rows
// Q pre-scale: 1/sqrt(64) * log2(e)  -> softmax via exp2
#define QSCL 0.18033688011112042591999058512524f

typedef short bf16x8 __attribute__((ext_vector_type(8)));
typedef float f32x16 __attribute__((ext_vector_type(16)));
typedef unsigned u32x2 __attribute__((ext_vector_type(2)));

__device__ __forceinline__ unsigned short bf16_rne(float x) {
    unsigned u = __float_as_uint(x);
    u += 0x7fffu + ((u >> 16) & 1u);
    return (unsigned short)(u >> 16);
}
__device__ __forceinline__ float bf16_tof(short h) {
    return __uint_as_float(((unsigned)(unsigned short)h) << 16);
}
// pack two f32 -> one u32 of 2x bf16 (RNE); no builtin on gfx950 (m240)
__device__ __forceinline__ unsigned cvtpk(float lo, float hi) {
    unsigned r;
    asm("v_cvt_pk_bf16_f32 %0, %1, %2" : "=v"(r) : "v"(lo), "v"(hi));
    return r;
}

__device__ __forceinline__ void gl_lds16(const void* g, void* s) {
    __builtin_amdgcn_global_load_lds(
        (const __attribute__((address_space(1))) unsigned int*)g,
        (__attribute__((address_space(3))) unsigned int*)s, 16, 0, 0);
}

__device__ __forceinline__ f32x16 mfma32(bf16x8 a, bf16x8 b, f32x16 c) {
    return __builtin_amdgcn_mfma_f32_32x32x16_bf16(a, b, c, 0, 0, 0);
}

// GEMM frag read: 128-B LDS rows (BK=64), 8 blocks of 16 B
__device__ __forceinline__ bf16x8 gfrag128(const char* base, int row, int physblk) {
    return *(const bf16x8*)(base + row * 128 + physblk * 16);
}
// Attention frag read: 128-B LDS rows, 8 blocks of 16 B, key row&7
__device__ __forceinline__ bf16x8 afrag(const short* base, int row, int blk) {
    return *(const bf16x8*)(base + row * 64 + ((blk ^ (row & 7)) << 3));
}

// ---------------------------------------------------------------------------
// Merged pre-pass. Blocks [0,1536): x fp32 -> bf16 (key (m>>1)&3).
// Blocks [1536, 2688): W transpose+convert, z = (b-1536)/288.
// z<3 (Wq,Wk,Wv) -> wqkv region; z==3 (Wo) -> wo region.
// ---------------------------------------------------------------------------
__global__ __launch_bounds__(256)
void conv_all(const float* __restrict__ x,
              const float* __restrict__ Wq, const float* __restrict__ Wk,
              const float* __restrict__ Wv, const float* __restrict__ Wo,
              short* __restrict__ xg, short* __restrict__ wqkv,
              short* __restrict__ wo)
{
    int b = blockIdx.x;
    if (b < 1536) {
        const int idx = b * 256 + threadIdx.x;   // 4096*96
        const int m = idx / 96, bk = idx % 96;
        const float* src = x + (size_t)m * DM + bk * 8;
        float4 v0 = *(const float4*)src;
        float4 v1 = *(const float4*)(src + 4);
        const float vv[8] = {v0.x, v0.y, v0.z, v0.w, v1.x, v1.y, v1.z, v1.w};
        union { short s[8]; int4 q; } hh;
#pragma unroll
        for (int j = 0; j < 8; j++) hh.s[j] = (short)bf16_rne(vv[j]);
        const int pb = (bk & ~3) | ((bk & 3) ^ ((m >> 1) & 3));
        *(int4*)(xg + (size_t)m * DM + pb * 8) = hh.q;
    } else {
        b -= 1536;
        const int z = b / 288;
        const float* __restrict__ W = (z == 0) ? Wq : (z == 1) ? Wk : (z == 2) ? Wv : Wo;
        short* __restrict__ wdst = (z == 3) ? wo : (wqkv + (size_t)z * 589824);
        const int idx = (b % 288) * 256 + threadIdx.x;   // 96*768
        const int n = idx % 768, bk = idx / 768;
        union { short s[8]; int4 q; } hh;
#pragma unroll
        for (int j = 0; j < 8; j++) hh.s[j] = (short)bf16_rne(W[(size_t)(bk * 8 + j) * DM + n]);
        const int pb = (bk & ~3) | ((bk & 3) ^ ((n >> 1) & 3));
        *(int4*)(wdst + (size_t)n * DM + pb * 8) = hh.q;
    }
}

// ---------------------------------------------------------------------------
// QKV K-loop — R28 config (proven best: BK=64, 12 iters, 8 MFMA/wave per
// barrier). Tile 64M x 128N, 6 gl_lds/iter, one barrier/iter. LDS 48 KB
// -> 3 blocks/CU. Swizzle: sel=(row>>1)&3 valid since all row offsets
// (32/64/96) are 0 mod 8. SWAP=true computes Y^T (reg-rows = n).
// ---------------------------------------------------------------------------
template<bool SWAP>
__device__ __forceinline__ void qkv_loop(const char* pA, const char* pB,
                                         char* As, char* Bs,
                                         int t, f32x16* acc)
{
    const int w = t >> 6, l = t & 63;
    const int q32 = l & 31, half = l >> 5;
    const int sel = (q32 >> 1) & 3;
    const int arow  = 32 * (w & 1) + q32;
    const int brow0 = 64 * (w >> 1) + q32;
    char* const dA = As + w * 1024;   // wave-uniform DMA dest (HW adds lane*16)
    char* const dB = Bs + w * 1024;

    auto stage = [&](int ki, int buf) {
        const size_t cb = (size_t)ki * 128;
        gl_lds16(pA + cb,             dA + buf * 8192);
        gl_lds16(pA + 32 * 1536 + cb, dA + buf * 8192 + 4096);
        gl_lds16(pB + cb,             dB + buf * 16384);
        gl_lds16(pB + 32 * 1536 + cb, dB + buf * 16384 + 4096);
        gl_lds16(pB + 64 * 1536 + cb, dB + buf * 16384 + 8192);
        gl_lds16(pB + 96 * 1536 + cb, dB + buf * 16384 + 12288);
    };

    stage(0, 0);
    __syncthreads();

    for (int ki = 0; ki < 12; ki++) {
        const int cur = ki & 1;
        if (ki < 11) stage(ki + 1, cur ^ 1);
        const char* sA = As + cur * 8192;
        const char* sB = Bs + cur * 16384;
#pragma unroll
        for (int ks2 = 0; ks2 < 4; ks2++) {
            const int b = ks2 * 2 + half;
            const int blk = (b & ~3) | ((b & 3) ^ sel);
            bf16x8 a  = gfrag128(sA, arow, blk);
            bf16x8 b0 = gfrag128(sB, brow0, blk);
            bf16x8 b1 = gfrag128(sB, brow0 + 32, blk);
            if (SWAP) {
                acc[0] = mfma32(b0, a, acc[0]);
                acc[1] = mfma32(b1, a, acc[1]);
            } else {
                acc[0] = mfma32(a, b0, acc[0]);
                acc[1] = mfma32(a, b1, acc[1]);
            }
        }
        __syncthreads();
    }
}

// ---------------------------------------------------------------------------
// QKV GEMM. grid (6, 64, 3), block 256 (4 waves, each 32M x 64N).
// z<2 computes Y^T -> packed uint2 Q/K epilogue into [b][h][s][64]
// (key s&7). z==2 computes Y -> packed uint2 into V^T [b][h][hd][2048]
// (key hd&7). LDS 48 KB (double-buffered, BK=64). R29's
// __launch_bounds__(256,3) was null -> removed (R28 exact).
// ---------------------------------------------------------------------------
__global__ __launch_bounds__(256)
void gemm_qkv(const short* __restrict__ xg, const short* __restrict__ wqkv,
              const float* __restrict__ bq, const float* __restrict__ bkv,
              const float* __restrict__ bv,
              short* __restrict__ qg, short* __restrict__ kg, short* __restrict__ vg)
{
    const int z = blockIdx.z;
    const short* __restrict__ Bw = wqkv + (size_t)z * 589824;
    const float* __restrict__ bias = (z == 0) ? bq : (z == 1) ? bkv : bv;

    __shared__ char As[16384], Bs[32768];
    const int t = threadIdx.x, w = t >> 6, l = t & 63;
    const int m0 = blockIdx.y * 64, n0 = blockIdx.x * 128;
    const int q32 = l & 31, half = l >> 5;

    // BK=64 staging: thread t covers row t>>3, 16-B chunk t&7 of a 128-B row
    const char* pA = (const char*)xg + (size_t)(m0 + (t >> 3)) * 1536 + (t & 7) * 16;
    const char* pB = (const char*)Bw + (size_t)(n0 + (t >> 3)) * 1536 + (t & 7) * 16;

    f32x16 acc[2];
#pragma unroll
    for (int i = 0; i < 2; i++)
#pragma unroll
        for (int r = 0; r < 16; r++) acc[i][r] = 0.f;

    if (z == 2) {
        qkv_loop<false>(pA, pB, As, Bs, t, acc);
        // V^T epilogue: reg-rows = m (4 consecutive s) -> uint2 stores
        const int nbase = n0 + 64 * (w >> 1);
        const int h = nbase >> 6;
        const int mbase = m0 + 32 * (w & 1) + 4 * half;
        const int bb = mbase >> 11;
#pragma unroll
        for (int nt = 0; nt < 2; nt++) {
            const int hd = 32 * nt + q32;
            const float bia = bias[nbase + hd];
            short* vrow = vg + ((size_t)(bb * NH + h) * HD + hd) * SEQ;
#pragma unroll
            for (int g = 0; g < 4; g++) {
                const int ss0 = (mbase & 2047) + 8 * g;
                union { unsigned short u[4]; uint2 q; } pk;
#pragma unroll
                for (int j = 0; j < 4; j++)
                    pk.u[j] = bf16_rne(acc[nt][4 * g + j] + bia);
                const int blk = ss0 >> 3;
                const int phys = (blk & ~7) | ((blk & 7) ^ (hd & 7));
                *(uint2*)(vrow + phys * 8 + (ss0 & 7)) = pk.q;
            }
        }
    } else {
        qkv_loop<true>(pA, pB, As, Bs, t, acc);
        // Q/K epilogue: reg-rows = n (4 consecutive hd) -> uint2 stores
        short* dst = (z == 0) ? qg : kg;
        const float scl = (z == 0) ? QSCL : 1.0f;
        const int mcol = m0 + 32 * (w & 1) + q32;
        const int bb = mcol >> 11, ss = mcol & 2047;
        const int h = (n0 + 64 * (w >> 1)) >> 6;
        short* drow = dst + ((size_t)(bb * NH + h) * SEQ + ss) * HD;
#pragma unroll
        for (int nt = 0; nt < 2; nt++)
#pragma unroll
            for (int g = 0; g < 4; g++) {
                const int hd0 = 32 * nt + 8 * g + 4 * half;
                float4 b4 = *(const float4*)&bias[(h << 6) + hd0];
                const float bb4[4] = {b4.x, b4.y, b4.z, b4.w};
                union { unsigned short u[4]; uint2 q; } pk;
#pragma unroll
                for (int j = 0; j < 4; j++)
                    pk.u[j] = bf16_rne((acc[nt][4 * g + j] + bb4[j]) * scl);
                const int phys = (hd0 >> 3) ^ (ss & 7);
                *(uint2*)(drow + phys * 8 + (hd0 & 7)) = pk.q;
            }
    }
}

// ---------------------------------------------------------------------------
// MFMA flash attention — exact R24 kernel (proven 47-50 us, best).
// R21 pipeline + __launch_bounds__(256, 3). exp2f is OCML — precision
// load-bearing (R22 lesson). Pipeline: prefetch(k+2) -> exp/pack(k) ->
// QK(k+1) -> PV(k); 3-slot ring, rotating pointers, z16-C-operand,
// T1 XCD remap. grid 768.
// ---------------------------------------------------------------------------
__global__ __launch_bounds__(256, 3)
void attn_mfma(const short* __restrict__ qg, const short* __restrict__ kg,
               const short* __restrict__ vg,
               short* __restrict__ opart, float* __restrict__ lpart)
{
    __shared__ __align__(16) short lds[24576];   // 48 KB: 3 slots of 16 KB (K 8KB + V 8KB)
    short* const sl0 = lds + 8192;
    short* const sl1 = lds + 16384;
    short* const sl2 = lds;                      // Q region until tile 2

    const int t = threadIdx.x, w = t >> 6, l = t & 63;
    const int f = (blockIdx.x & 7) * 96 + (blockIdx.x >> 3);   // T1 bijective remap
    const int q0 = (f & 15) * 128;
    const int bh = (f >> 4) % 24;
    const int ks = f / 384;
    const char* qp = (const char*)(qg + (size_t)bh * SEQ * HD);
    const char* kp = (const char*)(kg + (size_t)bh * SEQ * HD);
    const char* vp = (const char*)(vg + (size_t)bh * HD * SEQ);
    const int kbase = ks * 1024;

    auto stage_kv = [&](int tile, short* dst) {
        const int kb0 = kbase + tile * 64;
#pragma unroll
        for (int i = 0; i < 2; i++) {
            gl_lds16(kp + (size_t)(kb0 + w * 16 + i * 8) * 128 + l * 16,
                     (char*)dst + (w * 16 + i * 8) * 128);
            gl_lds16(vp + (size_t)(w * 16 + i * 8 + (l >> 3)) * 4096 + kb0 * 2 + (l & 7) * 16,
                     (char*)(dst + 4096) + (w * 16 + i * 8) * 128);
        }
    };

    // prologue: Q (wave-local rows) + tiles 0,1
#pragma unroll
    for (int i = 0; i < 4; i++)
        gl_lds16(qp + (size_t)(q0 + w * 32 + i * 8) * 128 + l * 16,
                 (char*)lds + (w * 32 + i * 8) * 128);
    stage_kv(0, sl0);
    stage_kv(1, sl1);

    asm volatile("s_waitcnt vmcnt(8)" ::: "memory");   // own Q DMA done (8 K/V ops in flight)

    const int half = l >> 5;
    const int q = l & 31;
    bf16x8 qf[4];
#pragma unroll
    for (int s = 0; s < 4; s++)
        qf[s] = afrag(lds, w * 32 + q, half + s * 2);
    __syncthreads();   // drains tiles 0,1 DMA; all waves' Q reads done (slot2 reusable)

    f32x16 oacc[2], lacc, z16;
#pragma unroll
    for (int r = 0; r < 16; r++) z16[r] = 0.f;
#pragma unroll
    for (int nt = 0; nt < 2; nt++)
#pragma unroll
        for (int r = 0; r < 16; r++) oacc[nt][r] = 0.f;
#pragma unroll
    for (int r = 0; r < 16; r++) lacc[r] = 0.f;

    bf16x8 onesf;
#pragma unroll
    for (int j = 0; j < 8; j++) onesf[j] = (short)0x3F80;   // bf16 1.0

    // rotating slot pointers: at iter k, scur=slot(k), snxt=slot(k+1),
    // spre=slot(k+2)==slot(k-1)
    short* scur = sl0;
    short* snxt = sl1;
    short* spre = sl2;

    // QK(0): first MFMA of each chain takes z16 as C (no zero-init movs)
    f32x16 sacc[2];
#pragma unroll
    for (int nt = 0; nt < 2; nt++)
        sacc[nt] = mfma32(afrag(sl0, nt * 32 + q, half), qf[0], z16);
#pragma unroll
    for (int s = 1; s < 4; s++)
#pragma unroll
        for (int nt = 0; nt < 2; nt++)
            sacc[nt] = mfma32(afrag(sl0, nt * 32 + q, half + s * 2), qf[s], sacc[nt]);

    for (int kti = 0; kti < 16; kti++) {
        // prefetch tile kti+2 into spre (== slot of tile kti-1) — issued
        // FIRST so the DMA has the exp/pack + MFMA phases to land
        if (kti < 14) stage_kv(kti + 2, spre);

        // P(kti) = exp2(S) in place (OCML exp2f — precision load-bearing)
#pragma unroll
        for (int nt = 0; nt < 2; nt++)
#pragma unroll
            for (int r = 0; r < 16; r++) sacc[nt][r] = exp2f(sacc[nt][r]);

        // pack all 4 PV A-fragments (T12); sacc is dead afterwards
        bf16x8 pfs[4];
#pragma unroll
        for (int s = 0; s < 4; s++) {
            const int nt = s >> 1;
            const int rb = (s & 1) * 8;
            const unsigned p0 = cvtpk(sacc[nt][rb + 0], sacc[nt][rb + 1]);
            const unsigned p1 = cvtpk(sacc[nt][rb + 2], sacc[nt][rb + 3]);
            const unsigned p2 = cvtpk(sacc[nt][rb + 4], sacc[nt][rb + 5]);
            const unsigned p3 = cvtpk(sacc[nt][rb + 6], sacc[nt][rb + 7]);
            const u32x2 w02 = __builtin_amdgcn_permlane32_swap(p0, p2, false, false);
            const u32x2 w13 = __builtin_amdgcn_permlane32_swap(p1, p3, false, false);
            union { unsigned u[4]; bf16x8 v; } pf;
            pf.u[0] = w02[0];   // keys 16s+8*half+{0,1}
            pf.u[1] = w13[0];   // keys 16s+8*half+{2,3}
            pf.u[2] = w02[1];   // keys 16s+8*half+{4,5}
            pf.u[3] = w13[1];   // keys 16s+8*half+{6,7}
            pfs[s] = pf.v;
        }

        // QK(kti+1) into reused sacc — fuses with PV below into one MFMA streak
        if (kti < 15) {
#pragma unroll
            for (int nt = 0; nt < 2; nt++)
                sacc[nt] = mfma32(afrag(snxt, nt * 32 + q, half), qf[0], z16);
#pragma unroll
            for (int s = 1; s < 4; s++)
#pragma unroll
                for (int nt = 0; nt < 2; nt++)
                    sacc[nt] = mfma32(afrag(snxt, nt * 32 + q, half + s * 2), qf[s], sacc[nt]);
        }

        // PV(kti): O += P V ; l += P @ ones
        const short* vc = scur + 4096;
#pragma unroll
        for (int s = 0; s < 4; s++) {
            lacc = mfma32(pfs[s], onesf, lacc);
#pragma unroll
            for (int nt2 = 0; nt2 < 2; nt2++)
                oacc[nt2] = mfma32(pfs[s], afrag(vc, nt2 * 32 + q, half + s * 2), oacc[nt2]);
        }
        __syncthreads();   // drains prefetch DMA; all waves done with scur

        short* tmp = scur; scur = snxt; snxt = spre; spre = tmp;
    }

    // epilogue: unnormalized partials
    const size_t base = (size_t)(ks * 24 + bh) * SEQ;
#pragma unroll
    for (int r = 0; r < 16; r++) {
        const int row = q0 + w * 32 + (r & 3) + 8 * (r >> 2) + 4 * half;
#pragma unroll
        for (int nt = 0; nt < 2; nt++)
            opart[(base + row) * 64 + nt * 32 + q] = (short)bf16_rne(oacc[nt][r]);
        if (q == 0) lpart[base + row] = lacc[r];
    }
}

// ---------------------------------------------------------------------------
// Combine K-split partials: ag = (O0+O1)/(l0+l1), bf16, key (m>>1)&3.
// grid 1536, block 256 (thread = 8 hd of one row).
// ---------------------------------------------------------------------------
__global__ __launch_bounds__(256)
void attn_reduce(const short* __restrict__ opart, const float* __restrict__ lpart,
                 short* __restrict__ ag)
{
    const int idx = blockIdx.x * 256 + threadIdx.x;   // 49152*8
    const int cg = idx & 7, row = idx >> 3;
    const int bh = row >> 11, s = row & 2047;
    union { short s[8]; int4 q; } a, b, o;
    a.q = *(const int4*)(opart + ((size_t)bh * SEQ + s) * 64 + cg * 8);
    b.q = *(const int4*)(opart + ((size_t)(24 + bh) * SEQ + s) * 64 + cg * 8);
    const float inv = 1.0f / (lpart[(size_t)bh * SEQ + s] + lpart[(size_t)(24 + bh) * SEQ + s]);
#pragma unroll
    for (int j = 0; j < 8; j++)
        o.s[j] = (short)bf16_rne((bf16_tof(a.s[j]) + bf16_tof(b.s[j])) * inv);
    const int bb = bh / NH, h = bh % NH;
    const int m = bb * SEQ + s;
    const int blk = h * 8 + cg;
    const int phys = (blk & ~3) | ((blk & 3) ^ ((m >> 1) & 3));
    *(int4*)(ag + (size_t)m * DM + phys * 8) = o.q;
}

// ---------------------------------------------------------------------------
// Output projection — R26/R28 config (proven: BK=64, 12 iters, 4
// MFMA/wave per barrier). Tile 64M x 64N, grid (12, 64), LDS 32 KB.
// Computed transposed (reg-rows = n) -> float4 epilogue. R29's
// __launch_bounds__(256,5) was null -> removed (R28 exact).
// ---------------------------------------------------------------------------
__global__ __launch_bounds__(256)
void gemm_out(const short* __restrict__ ag, const short* __restrict__ wt3,
              const float* __restrict__ bias, float* __restrict__ out)
{
    __shared__ char As[16384], Bs[16384];
    const int t = threadIdx.x, w = t >> 6, l = t & 63;
    const int m0 = blockIdx.y * 64, n0 = blockIdx.x * 64;
    const int q32 = l & 31, half = l >> 5;
    const int sel = (q32 >> 1) & 3;

    // BK=64 staging: thread t covers row t>>3, 16-B chunk t&7 of a 128-B row
    const char* pA = (const char*)ag  + (size_t)(m0 + (t >> 3)) * 1536 + (t & 7) * 16;
    const char* pB = (const char*)wt3 + (size_t)(n0 + (t >> 3)) * 1536 + (t & 7) * 16;
    char* const dA = As + w * 1024;   // wave-uniform DMA dest
    char* const dB = Bs + w * 1024;

    const int arow = 32 * (w & 1) + q32;
    const int brow = 32 * (w >> 1) + q32;

    f32x16 acc;
#pragma unroll
    for (int r = 0; r < 16; r++) acc[r] = 0.f;

    auto stage = [&](int ki, int buf) {
        const size_t cb = (size_t)ki * 128;
        gl_lds16(pA + cb,             dA + buf * 8192);          // rows 0-31
        gl_lds16(pA + 32 * 1536 + cb, dA + buf * 8192 + 4096);   // rows 32-63
        gl_lds16(pB + cb,             dB + buf * 8192);
        gl_lds16(pB + 32 * 1536 + cb, dB + buf * 8192 + 4096);
    };

    stage(0, 0);
    __syncthreads();

    for (int ki = 0; ki < 12; ki++) {
        const int cur = ki & 1;
        if (ki < 11) stage(ki + 1, cur ^ 1);
        const char* sA = As + cur * 8192;
        const char* sB = Bs + cur * 8192;
#pragma unroll
        for (int ks2 = 0; ks2 < 4; ks2++) {
            const int b = ks2 * 2 + half;
            const int blk = (b & ~3) | ((b & 3) ^ sel);
            acc = mfma32(gfrag128(sB, brow, blk), gfrag128(sA, arow, blk), acc);
        }
        __syncthreads();
    }

    const int mcol = m0 + 32 * (w & 1) + q32;
    const int nb0 = n0 + 32 * (w >> 1) + 4 * half;
#pragma unroll
    for (int g = 0; g < 4; g++) {
        const int ng = nb0 + 8 * g;
        float4 b4 = *(const float4*)&bias[ng];
        float4 o;
        o.x = acc[4 * g + 0] + b4.x;
        o.y = acc[4 * g + 1] + b4.y;
        o.z = acc[4 * g + 2] + b4.z;
        o.w = acc[4 * g + 3] + b4.w;
        *(float4*)&out[(size_t)mcol * DM + ng] = o;
    }
}

// ---------------------------------------------------------------------------
// Workspace layout (lifetime-aliased; R15 placement). Units: shorts.
//   wo    @ 0          size 589824      (conv -> gemm_out)
//   qg    @ 589824     size BUF         (qkv -> attn)
//   kg, vg             size BUF each
//   opart @ vg+BUF     size 2*24*2048*64 = 6291456    (attn -> reduce)
//   lpart @ opart+6291456   size 98304 floats         (attn -> reduce)
//   xg    @ = opart    size BUF         (conv -> qkv; dead before attn)  [alias]
//   wqkv  @ xg+BUF     size 3*589824    (conv -> qkv; dead before attn)  [alias]
//   ag    @ = qg       size BUF         (reduce -> out; qg dead)         [alias]
// ---------------------------------------------------------------------------
extern "C" void kernel_launch(void* const* d_in, const int* in_sizes, int n_in,
                              void* d_out, int out_size, void* d_ws, size_t ws_size,
                              hipStream_t stream)
{
    const float* x  = (const float*)d_in[0];
    const float* Wq = (const float*)d_in[1];
    const float* bq = (const float*)d_in[2];
    const float* Wk = (const float*)d_in[3];
    const float* bk = (const float*)d_in[4];
    const float* Wv = (const float*)d_in[5];
    const float* bv = (const float*)d_in[6];
    const float* Wo = (const float*)d_in[7];
    const float* bo = (const float*)d_in[8];
    float* out = (float*)d_out;

    const size_t BUF = (size_t)MT * DM;   // 3,145,728 elements
    short* base  = (short*)d_ws;
    short* wo    = base;
    short* qg    = base + 589824;
    short* kg    = qg + BUF;
    short* vg    = kg + BUF;
    short* opart = vg + BUF;                         // 2x partials
    float* lpart = (float*)(opart + (size_t)2 * 24 * SEQ * HD);
    short* xg    = opart;                            // alias (dead before attn)
    short* wqkv  = xg + BUF;                         // alias (dead before attn)
    short* ag    = qg;                               // alias (qg dead at reduce)

    conv_all<<<2688, 256, 0, stream>>>(x, Wq, Wk, Wv, Wo, xg, wqkv, wo);
    gemm_qkv<<<dim3(6, 64, 3), 256, 0, stream>>>(xg, wqkv, bq, bk, bv, qg, kg, vg);
    attn_mfma<<<768, 256, 0, stream>>>(qg, kg, vg, opart, lpart);
    attn_reduce<<<1536, 256, 0, stream>>>(opart, lpart, ag);
    gemm_out<<<dim3(12, 64), 256, 0, stream>>>(ag, wo, bo, out);
}